// Round 14
// baseline (374.723 us; speedup 1.0000x reference)
//
#include <hip/hip_runtime.h>
#include <math.h>

#define NN 50000
#define EE 1600000
#define GG 256
#define PAD 80         // padded slots per node; deg mean 32, sigma 5.66 -> 10 sigma
#define NB 256         // edge chunks
#define EPB 6250       // edges per chunk = EE/NB
#define NR 8           // dst ranges (XCD affinity)
#define RNG 6250       // dsts per range
#define BCAP 960       // bucket capacity per (chunk,range)
#define BNPB 512       // bn partial blocks (no data atomics: unique-slot stores)
#define BNPR 98        // rows per bn partial block (512*98 = 50176 >= NN)

constexpr float NEG = 0.2f;
constexpr float BN_EPS = 1e-5f;

typedef __attribute__((ext_vector_type(8))) short short8;
typedef __attribute__((ext_vector_type(4))) float f32x4;
typedef __attribute__((ext_vector_type(2))) float f32x2;

// param block offsets (floats), dict order of d_in[3..18]
constexpr int PB_W1 = 0, PB_A1S = 16384, PB_A1D = 16512, PB_B1 = 16640,
              PB_G1 = 16768, PB_BE1 = 16896, PB_W2 = 17024, PB_A2S = 33408,
              PB_A2D = 33536, PB_B2 = 33664, PB_G2 = 33792, PB_BE2 = 33920,
              PB_L1W = 34048, PB_L1B = 50432, PB_L2W = 50560, PB_L2B = 50816,
              PB_TOTAL = 50818;

struct PtrPack { const void* p[16]; };

__device__ __forceinline__ float b2f(unsigned short u) {
  unsigned v = ((unsigned)u) << 16;
  float f;
  __builtin_memcpy(&f, &v, 4);
  return f;
}
__device__ __forceinline__ float b2f_lo(unsigned u) {
  unsigned v = u << 16;
  float f;
  __builtin_memcpy(&f, &v, 4);
  return f;
}
__device__ __forceinline__ float b2f_hi(unsigned u) {
  unsigned v = u & 0xffff0000u;
  float f;
  __builtin_memcpy(&f, &v, 4);
  return f;
}
__device__ __forceinline__ unsigned short f2b(float f) {
  unsigned x;
  __builtin_memcpy(&x, &f, 4);
  unsigned r = x + 0x7FFFu + ((x >> 16) & 1u);
  return (unsigned short)(r >> 16);
}

// packed dual-FMA: acc.{x,y} += {bf16lo(u), bf16hi(u)} * wp.{x,y}
__device__ __forceinline__ void pkfma(f32x2& acc, unsigned u, f32x2 wp) {
  f32x2 p = {b2f_lo(u), b2f_hi(u)};
  asm("v_pk_fma_f32 %0, %1, %2, %0" : "+v"(acc) : "v"(p), "v"(wp));
}

// prep (block-split fusion): blocks 0..NB-1 = edge phase (histogram, phase-A
// bucketing, packed hist dump); blocks NB..NB+255 = misc phase (dtype detect,
// params, Wt1, starts, zeros). Independent phases share one launch (gap saved).
__global__ __launch_bounds__(512) void k_prep(PtrPack pk, const unsigned short* __restrict__ xb,
                                              const int* __restrict__ batch,
                                              const int* __restrict__ esrc,
                                              const int* __restrict__ edst,
                                              int* __restrict__ flag,
                                              float* __restrict__ pb,
                                              int* __restrict__ starts,
                                              int* __restrict__ ctrs,
                                              unsigned char* __restrict__ hist,
                                              unsigned* __restrict__ buck, int* __restrict__ bcnt,
                                              unsigned short* __restrict__ Wt1,
                                              float* __restrict__ poolsum) {
  __shared__ unsigned hcnt[25000];   // 2 x u16 packed per word (edge blocks)
  __shared__ int bc[NR];
  __shared__ int cs;
  int bid = blockIdx.x, t = threadIdx.x;
  if (bid < NB) {
    int c = bid;
    if (t < NR) bc[t] = 0;
    for (int j = t; j < 25000; j += 512) hcnt[j] = 0u;
    __syncthreads();
    int e0 = c * EPB;
    for (int i = t; i < EPB; i += 512) {
      int e = e0 + i;
      int d = edst[e];
      if ((unsigned)d >= (unsigned)NN) continue;
      int s = esrc[e];
      if ((unsigned)s >= (unsigned)NN) s = 0;
      int sh = (d & 1) * 16;
      unsigned old = atomicAdd(&hcnt[d >> 1], 1u << sh);
      unsigned rank = (old >> sh) & 0xFFFFu;
      if (rank > 7u) continue;
      int r = d / RNG;
      int dl = d - r * RNG;
      int pos = atomicAdd(&bc[r], 1);
      if (pos < BCAP)
        buck[(c * NR + r) * BCAP + pos] = ((unsigned)s << 16) | ((unsigned)dl << 3) | rank;
    }
    __syncthreads();
    if (t < NR) bcnt[c * NR + t] = min(bc[t], BCAP);
    // packed hist dump: 4 counts per uint store (NN % 4 == 0)
    unsigned* hw = (unsigned*)(hist + c * NN);
    for (int j = t; j < NN / 4; j += 512) {
      unsigned w0 = hcnt[2 * j], w1 = hcnt[2 * j + 1];
      unsigned b0 = min(w0 & 0xFFFFu, 255u), b1 = min(w0 >> 16, 255u);
      unsigned b2 = min(w1 & 0xFFFFu, 255u), b3 = min(w1 >> 16, 255u);
      hw[j] = b0 | (b1 << 8) | (b2 << 16) | (b3 << 24);
    }
  } else {
    const int segoff[17] = {0, 16384, 16512, 16640, 16768, 16896, 17024, 33408,
                            33536, 33664, 33792, 33920, 34048, 50432, 50560, 50816, 50818};
    int c = bid - NB;
    if (t == 0) cs = 0;
    __syncthreads();
    int sane = 0;
    for (int i = t; i < 4096; i += 512) {
      float a = fabsf(b2f(xb[i]));
      if (a > 1e-4f && a < 100.f) sane++;
    }
    atomicAdd(&cs, sane);
    __syncthreads();
    int bf = (cs > 3482) ? 1 : 0;
    if (c == 0 && t == 0) *flag = bf;
    // params
    for (int j = t; j < 199; j += 512) {
      int i = c * 199 + j;
      if (i < PB_TOTAL) {
        int seg = 0;
        while (i >= segoff[seg + 1]) seg++;
        int k = i - segoff[seg];
        pb[i] = bf ? b2f(((const unsigned short*)pk.p[seg])[k]) : ((const float*)pk.p[seg])[k];
      }
    }
    // Wt1[n][k] = bf16(W1[k][n]): 64 elements per block
    for (int j = t; j < 64; j += 512) {
      int i = c * 64 + j;
      int n = i & 127, k = i >> 7;
      Wt1[n * 128 + k] = bf ? ((const unsigned short*)pk.p[0])[k * 128 + n]
                            : f2b(((const float*)pk.p[0])[k * 128 + n]);
    }
    // poolsum zero: 128 per block
    for (int j = t; j < 128; j += 512) poolsum[c * 128 + j] = 0.f;
    // starts
    for (int j = t; j < 196; j += 512) {
      int n = c * 196 + j;
      if (n < NN) {
        int bb = batch[n];
        bb = min(max(bb, 0), GG - 1);
        int bp = (n == 0) ? -1 : batch[n - 1];
        bp = min(max(bp, -1), GG - 1);
        for (int gg = bp + 1; gg <= bb; gg++) starts[gg] = n;
        if (n == NN - 1)
          for (int gg = bb + 1; gg <= GG; gg++) starts[gg] = NN;
      }
    }
    if (c == 255 && t < 8) ctrs[t] = 0;
  }
}

// MFMA GEMM: Y = X @ Wt^T + shiftW, B-fragments straight from global bf16 Wt[n][k].
__device__ __forceinline__ void gemm_body(float* cst, int bid,
                                          const unsigned short* __restrict__ Xb,
                                          const float* __restrict__ Xf, int bfm,
                                          const unsigned short* __restrict__ Wt,
                                          const float* __restrict__ shiftW,
                                          const float* __restrict__ aS,
                                          const float* __restrict__ aD,
                                          unsigned short* __restrict__ Y,
                                          float* __restrict__ as_, float* __restrict__ ad_) {
  int t = threadIdx.x;
  int row0 = bid * 64;
  int w = t >> 6, lane = t & 63;
  int m = lane & 15, quad = lane >> 4;
  int rA = min(row0 + w * 16 + m, NN - 1);
  short8 a4[4];
  if (bfm) {
    const short8* xp = (const short8*)(Xb + rA * 128);
#pragma unroll
    for (int kk = 0; kk < 4; kk++) a4[kk] = xp[kk * 4 + quad];
  } else {
#pragma unroll
    for (int kk = 0; kk < 4; kk++) {
      const float* xf = Xf + rA * 128 + kk * 32 + quad * 8;
#pragma unroll
      for (int j = 0; j < 8; j++) a4[kk][j] = (short)f2b(xf[j]);
    }
  }
  f32x4 acc[8] = {};
#pragma unroll
  for (int kk = 0; kk < 4; kk++) {
    int ko = kk * 32 + quad * 8;
#pragma unroll
    for (int n0 = 0; n0 < 8; n0++) {
      short8 b = *(const short8*)(Wt + (n0 * 16 + m) * 128 + ko);
      acc[n0] = __builtin_amdgcn_mfma_f32_16x16x32_bf16(a4[kk], b, acc[n0], 0, 0, 0);
    }
  }
  // C layout: col = lane&15, row = quad*4 + reg
#pragma unroll
  for (int n0 = 0; n0 < 8; n0++)
#pragma unroll
    for (int r = 0; r < 4; r++)
      cst[(w * 16 + quad * 4 + r) * 130 + n0 * 16 + m] = acc[n0][r];
  __syncthreads();
  int cg = t & 31, rg = t >> 5;
  int c0 = cg * 4;
  float a_s[4], a_d[4], sw[4];
#pragma unroll
  for (int j = 0; j < 4; j++) {
    a_s[j] = aS[c0 + j];
    a_d[j] = aD[c0 + j];
    sw[j] = shiftW[c0 + j];
  }
#pragma unroll
  for (int i = 0; i < 8; i++) {
    int rl = rg + i * 8;
    int row = row0 + rl;
    float v0 = cst[rl * 130 + c0 + 0] + sw[0];
    float v1 = cst[rl * 130 + c0 + 1] + sw[1];
    float v2 = cst[rl * 130 + c0 + 2] + sw[2];
    float v3 = cst[rl * 130 + c0 + 3] + sw[3];
    if (row < NN) {
      uint2 pk2;
      pk2.x = (unsigned)f2b(v0) | ((unsigned)f2b(v1) << 16);
      pk2.y = (unsigned)f2b(v2) | ((unsigned)f2b(v3) << 16);
      *reinterpret_cast<uint2*>(&Y[row * 128 + c0]) = pk2;
    }
    float ps = v0 * a_s[0] + v1 * a_s[1] + v2 * a_s[2] + v3 * a_s[3];
    float pd = v0 * a_d[0] + v1 * a_d[1] + v2 * a_d[2] + v3 * a_d[3];
    ps += __shfl_xor(ps, 1); ps += __shfl_xor(ps, 2); ps += __shfl_xor(ps, 4);
    pd += __shfl_xor(pd, 1); pd += __shfl_xor(pd, 2); pd += __shfl_xor(pd, 4);
    if ((cg & 7) == 0 && row < NN) {
      int hh = cg >> 3;
      as_[row * 4 + hh] = ps;
      ad_[row * 4 + hh] = pd;
    }
  }
}

// fused: blocks 0..195 = in-place base scan over hist (16-way batched loads);
// blocks 196.. = layer-1 GEMM.
__global__ __launch_bounds__(256) void k_basegemm(unsigned char* __restrict__ hist,
                                                  int* __restrict__ cnt,
                                                  const unsigned short* __restrict__ Xb,
                                                  const float* __restrict__ Xf,
                                                  const int* __restrict__ flagp,
                                                  const unsigned short* __restrict__ Wt,
                                                  const float* __restrict__ shiftW,
                                                  const float* __restrict__ aS,
                                                  const float* __restrict__ aD,
                                                  unsigned short* __restrict__ Y,
                                                  float* __restrict__ as_, float* __restrict__ ad_) {
  __shared__ float cst[64 * 130];
  int idx = blockIdx.x;
  if (idx < 196) {
    int d = idx * 256 + threadIdx.x;
    if (d >= NN) return;
    int run = 0;
    for (int b = 0; b < NB; b += 16) {
      unsigned char h[16];
#pragma unroll
      for (int j = 0; j < 16; j++) h[j] = hist[(b + j) * NN + d];   // 16 loads in flight
#pragma unroll
      for (int j = 0; j < 16; j++) {
        hist[(b + j) * NN + d] = (unsigned char)min(run, 255);      // in-place: becomes base
        run += h[j];
      }
    }
    cnt[d] = run;
  } else {
    gemm_body(cst, idx - 196, Xb, Xf, *flagp, Wt, shiftW, aS, aD, Y, as_, ad_);
  }
}

// phase-B fill alone: 256 XCD-affine blocks (range r = bid&7).
__global__ __launch_bounds__(256) void k_fill(const unsigned* __restrict__ buck,
                                              const int* __restrict__ bcnt,
                                              const unsigned char* __restrict__ base,
                                              unsigned short* __restrict__ adj) {
  int idx = blockIdx.x;
  int t = threadIdx.x;
  int r = idx & 7, g = idx >> 3;
  int dbase = r * RNG;
#pragma unroll 1
  for (int j = 0; j < 8; j++) {
    int c = g * 8 + j;
    int n = bcnt[c * NR + r];
    const unsigned* bk = buck + (c * NR + r) * BCAP;
    const unsigned char* bs = base + c * NN;
    for (int i = t; i < n; i += 256) {
      unsigned p = bk[i];
      int s = p >> 16;
      int dl = (p >> 3) & 0x1FFF;
      int rank = p & 7;
      int d = dbase + dl;
      int slot = (int)bs[d] + rank;
      if (slot < PAD) adj[d * PAD + slot] = (unsigned short)s;
    }
  }
}

__global__ __launch_bounds__(256) void k_gemm(const unsigned short* __restrict__ Xb,
                                              const unsigned short* __restrict__ Wt,
                                              const float* __restrict__ shiftW,
                                              const float* __restrict__ aS,
                                              const float* __restrict__ aD,
                                              unsigned short* __restrict__ Y,
                                              float* __restrict__ as_, float* __restrict__ ad_) {
  __shared__ float cst[64 * 130];
  gemm_body(cst, blockIdx.x, Xb, nullptr, 1, Wt, shiftW, aS, aD, Y, as_, ad_);
}

// one WAVE per dst (4 nodes / 256-thread block), wave-synchronous.
// nbase: node offset — 3 range dispatches per layer (visibility probe r14:
// ceiling ~18.3µs so [18,54]µs kernels surface in top-5). BW-bound at
// ~3.5 TB/s fabric (r3-r6) — gather structure unchanged.
__global__ __launch_bounds__(256) void k_agg(int nbase,
                                             const unsigned short* __restrict__ adj,
                                             const int* __restrict__ cnt,
                                             const float4* __restrict__ asrc4,
                                             const float4* __restrict__ adst4,
                                             const uint4* __restrict__ hin4,
                                             const float* __restrict__ bias,
                                             unsigned short* __restrict__ out) {
  __shared__ float wq2[4][4][PAD];     // [wave][head][slot]
  __shared__ unsigned soffs[4][PAD];   // [wave][slot] = src*256 (byte offset)
  int t = threadIdx.x;
  int wid = t >> 6, lane = t & 63;
  int n = nbase + blockIdx.x * 4 + wid;
  int deg = cnt[n];
  if (deg < 0) deg = 0;
  if (deg > PAD - 1) deg = PAD - 1;
  int tot = deg + 1;  // + self loop
  int W = (((tot + 3) >> 2) + 3) & ~3;  // per-group window, mult of 4, 4W <= PAD
  int WL = 4 * W;
  int beg = n * PAD;
  float4 ad4 = adst4[n];
  float ls0 = 0.f, ls1 = 0.f, ls2 = 0.f, ls3 = 0.f;
  for (int b = lane; b < WL; b += 64) {
    if (b < tot) {
      int s = (b < deg) ? (int)adj[beg + b] : n;
      if ((unsigned)s >= (unsigned)NN) s = n;
      float4 a = asrc4[s];
      float s0 = a.x + ad4.x; s0 = s0 > 0.f ? s0 : NEG * s0;
      float s1 = a.y + ad4.y; s1 = s1 > 0.f ? s1 : NEG * s1;
      float s2 = a.z + ad4.z; s2 = s2 > 0.f ? s2 : NEG * s2;
      float s3 = a.w + ad4.w; s3 = s3 > 0.f ? s3 : NEG * s3;
      float e0 = __expf(s0), e1 = __expf(s1), e2 = __expf(s2), e3 = __expf(s3);
      ls0 += e0; ls1 += e1; ls2 += e2; ls3 += e3;
      wq2[wid][0][b] = e0; wq2[wid][1][b] = e1;
      wq2[wid][2][b] = e2; wq2[wid][3][b] = e3;
      soffs[wid][b] = (unsigned)s * 256u;
    } else {
      wq2[wid][0][b] = 0.f; wq2[wid][1][b] = 0.f;
      wq2[wid][2][b] = 0.f; wq2[wid][3][b] = 0.f;
      soffs[wid][b] = (unsigned)n * 256u;
    }
  }
  // intra-wave LDS RAW ordering + compiler fence
  asm volatile("" ::: "memory");
  __builtin_amdgcn_wave_barrier();
  int g = lane >> 4, L = lane & 15, hd = L >> 2;
  const char* hb = (const char*)hin4;
  unsigned Loff = (unsigned)L * 16u;
  const float* wrow = &wq2[wid][hd][0];
  const unsigned* srow = &soffs[wid][0];
  f32x2 acc2[4] = {};
  int e0w = g * W, e1w = e0w + W;
  for (int e = e0w; e < e1w; e += 4) {
    f32x4 w4 = *(const f32x4*)(wrow + e);        // ds_read_b128
    uint4 o4 = *(const uint4*)(srow + e);        // ds_read_b128
    uint4 v1 = *(const uint4*)(hb + (o4.x + Loff));
    uint4 v2 = *(const uint4*)(hb + (o4.y + Loff));
    uint4 v3 = *(const uint4*)(hb + (o4.z + Loff));
    uint4 v4 = *(const uint4*)(hb + (o4.w + Loff));
    f32x2 p1 = {w4.x, w4.x}, p2 = {w4.y, w4.y}, p3 = {w4.z, w4.z}, p4 = {w4.w, w4.w};
    pkfma(acc2[0], v1.x, p1); pkfma(acc2[1], v1.y, p1);
    pkfma(acc2[2], v1.z, p1); pkfma(acc2[3], v1.w, p1);
    pkfma(acc2[0], v2.x, p2); pkfma(acc2[1], v2.y, p2);
    pkfma(acc2[2], v2.z, p2); pkfma(acc2[3], v2.w, p2);
    pkfma(acc2[0], v3.x, p3); pkfma(acc2[1], v3.y, p3);
    pkfma(acc2[2], v3.z, p3); pkfma(acc2[3], v3.w, p3);
    pkfma(acc2[0], v4.x, p4); pkfma(acc2[1], v4.y, p4);
    pkfma(acc2[2], v4.z, p4); pkfma(acc2[3], v4.w, p4);
  }
  // cross-group reduce: lanes L, L+16, L+32, L+48 hold the same 8 channels
#pragma unroll
  for (int j = 0; j < 4; j++) {
    acc2[j].x += __shfl_xor(acc2[j].x, 16);
    acc2[j].y += __shfl_xor(acc2[j].y, 16);
    acc2[j].x += __shfl_xor(acc2[j].x, 32);
    acc2[j].y += __shfl_xor(acc2[j].y, 32);
  }
  // softmax denominators: register-only butterfly
#pragma unroll
  for (int mm = 1; mm < 64; mm <<= 1) {
    ls0 += __shfl_xor(ls0, mm);
    ls1 += __shfl_xor(ls1, mm);
    ls2 += __shfl_xor(ls2, mm);
    ls3 += __shfl_xor(ls3, mm);
  }
  if (g == 0) {
    float den = (hd == 0) ? ls0 : (hd == 1) ? ls1 : (hd == 2) ? ls2 : ls3;
    float inv = 1.0f / (den + 1e-16f);
    const float4* bp = reinterpret_cast<const float4*>(bias + L * 8);
    float4 b0 = bp[0], b1 = bp[1];
    float o0 = acc2[0].x * inv + b0.x;
    float o1 = acc2[0].y * inv + b0.y;
    float o2 = acc2[1].x * inv + b0.z;
    float o3 = acc2[1].y * inv + b0.w;
    float o4 = acc2[2].x * inv + b1.x;
    float o5 = acc2[2].y * inv + b1.y;
    float o6 = acc2[3].x * inv + b1.z;
    float o7 = acc2[3].y * inv + b1.w;
    o0 = o0 > 0.f ? o0 : 0.f;
    o1 = o1 > 0.f ? o1 : 0.f;
    o2 = o2 > 0.f ? o2 : 0.f;
    o3 = o3 > 0.f ? o3 : 0.f;
    o4 = o4 > 0.f ? o4 : 0.f;
    o5 = o5 > 0.f ? o5 : 0.f;
    o6 = o6 > 0.f ? o6 : 0.f;
    o7 = o7 > 0.f ? o7 : 0.f;
    uint4 pk4;
    pk4.x = (unsigned)f2b(o0) | ((unsigned)f2b(o1) << 16);
    pk4.y = (unsigned)f2b(o2) | ((unsigned)f2b(o3) << 16);
    pk4.z = (unsigned)f2b(o4) | ((unsigned)f2b(o5) << 16);
    pk4.w = (unsigned)f2b(o6) | ((unsigned)f2b(o7) << 16);
    *reinterpret_cast<uint4*>(&out[n * 128 + L * 8]) = pk4;
  }
}

// BN partial sums, ZERO atomics, split-kernel handoff (r11 lesson: per-block
// __threadfence on non-coherent multi-XCD L2 costs ~67µs/dispatch — the
// KERNEL BOUNDARY is the cheap fence). Grid BNPB (stats only) or BNPB+GG
// (layer 2: + per-graph pooling blocks via starts[], no atomics).
__global__ __launch_bounds__(256) void k_bnpartial(const unsigned* __restrict__ x32,
                                                   float* __restrict__ partial,
                                                   const int* __restrict__ starts,
                                                   float* __restrict__ poolsum) {
  __shared__ float stg[4][256];
  int bid = blockIdx.x, t = threadIdx.x;
  int u = t & 63, ph = t >> 6;
  if (bid < BNPB) {
    int r0 = bid * BNPR, r1 = min(r0 + BNPR, NN);
    float s0 = 0.f, q0 = 0.f, s1 = 0.f, q1 = 0.f;
    for (int r = r0 + ph; r < r1; r += 4) {
      unsigned v = x32[r * 64 + u];
      float lo = b2f_lo(v), hi = b2f_hi(v);
      s0 += lo; q0 += lo * lo;
      s1 += hi; q1 += hi * hi;
    }
    stg[ph][2 * u] = s0;
    stg[ph][2 * u + 1] = s1;
    stg[ph][128 + 2 * u] = q0;
    stg[ph][128 + 2 * u + 1] = q1;
    __syncthreads();
    partial[bid * 256 + t] = stg[0][t] + stg[1][t] + stg[2][t] + stg[3][t];
  } else {
    int g = bid - BNPB;
    int b0 = starts[g], b1 = starts[g + 1];
    b0 = min(max(b0, 0), NN);
    b1 = min(max(b1, 0), NN);
    float p0 = 0.f, p1 = 0.f;
    for (int r = b0 + ph; r < b1; r += 4) {
      unsigned v = x32[r * 64 + u];
      p0 += b2f_lo(v);
      p1 += b2f_hi(v);
    }
    stg[ph][2 * u] = p0;
    stg[ph][2 * u + 1] = p1;
    __syncthreads();
    if (t < 128) poolsum[g * 128 + t] = stg[0][t] + stg[1][t] + stg[2][t] + stg[3][t];
  }
}

// BN finalize layer 1 (1 block): reduce partials, affine coefficients,
// Wt2/sw2 build (BN1 folded into layer-2 GEMM).
__global__ __launch_bounds__(256) void k_bnfinal(const float* __restrict__ partial,
                                                 const float* __restrict__ g, const float* __restrict__ b,
                                                 const float* __restrict__ W2f, float* __restrict__ sw2,
                                                 unsigned short* __restrict__ Wt2) {
  __shared__ float sums[256];
  __shared__ float shs[128];
  __shared__ float scs[128];
  int t = threadIdx.x;
  float acc = 0.f;
  for (int bb = 0; bb < BNPB; bb += 8) {
    float a0 = partial[(bb + 0) * 256 + t];
    float a1 = partial[(bb + 1) * 256 + t];
    float a2 = partial[(bb + 2) * 256 + t];
    float a3 = partial[(bb + 3) * 256 + t];
    float a4 = partial[(bb + 4) * 256 + t];
    float a5 = partial[(bb + 5) * 256 + t];
    float a6 = partial[(bb + 6) * 256 + t];
    float a7 = partial[(bb + 7) * 256 + t];
    acc += ((a0 + a1) + (a2 + a3)) + ((a4 + a5) + (a6 + a7));
  }
  sums[t] = acc;
  __syncthreads();
  if (t < 128) {
    float inv = 1.0f / NN;
    float mu = sums[t] * inv;
    float var = sums[128 + t] * inv - mu * mu;
    float rs = rsqrtf(var + BN_EPS);
    scs[t] = g[t] * rs;
    shs[t] = b[t] - mu * scs[t];
  }
  __syncthreads();
  if (t < 128) {
    float s = 0.f;
    for (int k = 0; k < 128; k++) s += shs[k] * W2f[k * 128 + t];
    sw2[t] = s;
  }
  // Wt2[n][k] = bf16(scale[k] * W2[k][n])
  for (int i = t; i < 16384; i += 256) {
    int n = i & 127, k = i >> 7;
    Wt2[n * 128 + k] = f2b(scs[k] * W2f[k * 128 + n]);
  }
}

// head with BN2-finalize fused in: each block redundantly reduces the
// L2-resident bnpart, derives scale2/shift2 in LDS, then computes its
// graph's pooled BN + MLP.
__global__ __launch_bounds__(256) void k_head(const float* __restrict__ partial,
                                              const float* __restrict__ poolsum,
                                              const int* __restrict__ starts,
                                              const float* __restrict__ g, const float* __restrict__ b,
                                              const float* __restrict__ L1W, const float* __restrict__ L1b,
                                              const float* __restrict__ L2W, const float* __restrict__ L2b,
                                              const int* __restrict__ flagp, void* __restrict__ outp) {
  __shared__ float sums[256];
  __shared__ float scs[128], shs[128];
  __shared__ float pooled[128];
  __shared__ float r0a[128], r1a[128];
  int gid = blockIdx.x, t = threadIdx.x;
  float acc = 0.f;
  for (int bb = 0; bb < BNPB; bb += 8) {
    float a0 = partial[(bb + 0) * 256 + t];
    float a1 = partial[(bb + 1) * 256 + t];
    float a2 = partial[(bb + 2) * 256 + t];
    float a3 = partial[(bb + 3) * 256 + t];
    float a4 = partial[(bb + 4) * 256 + t];
    float a5 = partial[(bb + 5) * 256 + t];
    float a6 = partial[(bb + 6) * 256 + t];
    float a7 = partial[(bb + 7) * 256 + t];
    acc += ((a0 + a1) + (a2 + a3)) + ((a4 + a5) + (a6 + a7));
  }
  sums[t] = acc;
  __syncthreads();
  if (t < 128) {
    float inv = 1.0f / NN;
    float mu = sums[t] * inv;
    float var = sums[128 + t] * inv - mu * mu;
    float rs = rsqrtf(var + BN_EPS);
    scs[t] = g[t] * rs;
    shs[t] = b[t] - mu * scs[t];
  }
  __syncthreads();
  int b0 = starts[gid], b1 = starts[gid + 1];
  b0 = min(max(b0, 0), NN);
  b1 = min(max(b1, 0), NN);
  int cnt = b1 - b0;
  if (t < 128) {
    float s = poolsum[gid * 128 + t];
    pooled[t] = (cnt > 0) ? (s / cnt) * scs[t] + shs[t] : 0.f;
  }
  __syncthreads();
  if (t < 128) {
    float z = L1b[t];
    for (int k = 0; k < 128; k++) z += pooled[k] * L1W[k * 128 + t];
    z = z > 0.f ? z : 0.f;
    r0a[t] = z * L2W[t * 2 + 0];
    r1a[t] = z * L2W[t * 2 + 1];
  }
  __syncthreads();
  for (int d = 64; d >= 1; d >>= 1) {
    if (t < d) {
      r0a[t] += r0a[t + d];
      r1a[t] += r1a[t + d];
    }
    __syncthreads();
  }
  if (t == 0) {
    float o0 = r0a[0] + L2b[0];
    float o1 = r1a[0] + L2b[1];
    if (*flagp) {
      unsigned short* ob = (unsigned short*)outp;
      ob[gid * 2 + 0] = f2b(o0);
      ob[gid * 2 + 1] = f2b(o1);
    } else {
      float* of = (float*)outp;
      of[gid * 2 + 0] = o0;
      of[gid * 2 + 1] = o1;
    }
  }
}

extern "C" void kernel_launch(void* const* d_in, const int* in_sizes, int n_in,
                              void* d_out, int out_size, void* d_ws, size_t ws_size,
                              hipStream_t stream) {
  (void)in_sizes; (void)n_in; (void)out_size; (void)ws_size;
  const int* ei = (const int*)d_in[1];
  const int* batch = (const int*)d_in[2];

  float* ws = (float*)d_ws;
  size_t o = 0;
  int* flag = (int*)(ws + o);   o += 16;
  int* ctrs = (int*)(ws + o);   o += 16;
  float* pb = ws + o;           o += 51200;
  float* bnpart = ws + o;       o += BNPB * 256;  // 512 KB partials, no atomics
  float* wzero = ws + o;        o += 128;
  float* sw2 = ws + o;          o += 128;
  unsigned short* Wt1 = (unsigned short*)(ws + o); o += 8192;
  unsigned short* Wt2 = (unsigned short*)(ws + o); o += 8192;
  float* poolsum = ws + o;      o += GG * 128;
  int* cnt = (int*)(ws + o);    o += 50016;
  int* starts = (int*)(ws + o); o += 512;
  int* bcnt = (int*)(ws + o);   o += 2048;
  float* asrc = ws + o;         o += 200000;
  float* adst = ws + o;         o += 200000;
  unsigned* buck = (unsigned*)(ws + o);            o += NB * NR * BCAP;  // 7.5 MB
  unsigned short* adj = (unsigned short*)(ws + o); o += NN * PAD / 2;    // 8 MB
  unsigned short* hA = (unsigned short*)(ws + o);  o += 3200000;         // 12.8 MB
  unsigned short* hB = (unsigned short*)(ws + o);  o += 3200000;         // 12.8 MB

  // hist/base share ONE buffer in hA-space (in-place scan): hA's real
  // lifetime starts at k_agg#1 output, after k_fill consumed base.
  unsigned char* hist = (unsigned char*)hA;

  const int* esrc = ei;
  const int* edst = ei + EE;

  PtrPack pk;
  for (int i = 0; i < 16; i++) pk.p[i] = d_in[3 + i];

  // fused prep: edge blocks (0..255) + misc blocks (256..511)
  k_prep<<<NB + 256, 512, 0, stream>>>(pk, (const unsigned short*)d_in[0], batch, esrc, edst,
                                       flag, pb, starts, ctrs, hist, buck, bcnt, Wt1, poolsum);

  // base scan (196 blocks, 16-way batched) || layer-1 MFMA gemm (782 blocks)
  k_basegemm<<<196 + 782, 256, 0, stream>>>(hist, cnt,
                                            (const unsigned short*)d_in[0], (const float*)d_in[0],
                                            flag, Wt1, wzero,
                                            pb + PB_A1S, pb + PB_A1D, hB, asrc, adst);
  k_fill<<<NB, 256, 0, stream>>>(buck, bcnt, hist, adj);

  // layer-1 aggregation: 3 node-range dispatches (visibility probe)
  k_agg<<<4167, 256, 0, stream>>>(0, adj, cnt, (const float4*)asrc, (const float4*)adst,
                                  (const uint4*)hB, pb + PB_B1, hA);
  k_agg<<<4167, 256, 0, stream>>>(16668, adj, cnt, (const float4*)asrc, (const float4*)adst,
                                  (const uint4*)hB, pb + PB_B1, hA);
  k_agg<<<4166, 256, 0, stream>>>(33336, adj, cnt, (const float4*)asrc, (const float4*)adst,
                                  (const uint4*)hB, pb + PB_B1, hA);
  k_bnpartial<<<BNPB, 256, 0, stream>>>((const unsigned*)hA, bnpart, starts, nullptr);
  k_bnfinal<<<1, 256, 0, stream>>>(bnpart, pb + PB_G1, pb + PB_BE1,
                                   pb + PB_W2, sw2, Wt2);

  // layer 2 (BN1 folded into Wt2/sw2)
  k_gemm<<<782, 256, 0, stream>>>(hA, Wt2, sw2, pb + PB_A2S, pb + PB_A2D, hB, asrc, adst);
  k_agg<<<4167, 256, 0, stream>>>(0, adj, cnt, (const float4*)asrc, (const float4*)adst,
                                  (const uint4*)hB, pb + PB_B2, hA);
  k_agg<<<4167, 256, 0, stream>>>(16668, adj, cnt, (const float4*)asrc, (const float4*)adst,
                                  (const uint4*)hB, pb + PB_B2, hA);
  k_agg<<<4166, 256, 0, stream>>>(33336, adj, cnt, (const float4*)asrc, (const float4*)adst,
                                  (const uint4*)hB, pb + PB_B2, hA);
  // stats partials + per-graph pooling (no atomics)
  k_bnpartial<<<BNPB + GG, 256, 0, stream>>>((const unsigned*)hA, bnpart, starts, poolsum);

  // head with fused BN2 finalize
  k_head<<<GG, 256, 0, stream>>>(bnpart, poolsum, starts,
                                 pb + PB_G2, pb + PB_BE2,
                                 pb + PB_L1W, pb + PB_L1B,
                                 pb + PB_L2W, pb + PB_L2B, flag, d_out);
}

// Round 15
// 355.722 us; speedup vs baseline: 1.0534x; 1.0534x over previous
//
#include <hip/hip_runtime.h>
#include <math.h>

#define NN 50000
#define EE 1600000
#define GG 256
#define PAD 80         // padded slots per node; deg mean 32, sigma 5.66 -> 10 sigma
#define NB 256         // edge chunks
#define EPB 6250       // edges per chunk = EE/NB
#define NR 8           // dst ranges (XCD affinity)
#define RNG 6250       // dsts per range
#define BCAP 960       // bucket capacity per (chunk,range)
#define BNPB 512       // bn partial blocks (no data atomics: unique-slot stores)
#define BNPR 98        // rows per bn partial block (512*98 = 50176 >= NN)

constexpr float NEG = 0.2f;
constexpr float BN_EPS = 1e-5f;

typedef __attribute__((ext_vector_type(8))) short short8;
typedef __attribute__((ext_vector_type(4))) float f32x4;
typedef __attribute__((ext_vector_type(2))) float f32x2;

// param block offsets (floats), dict order of d_in[3..18]
constexpr int PB_W1 = 0, PB_A1S = 16384, PB_A1D = 16512, PB_B1 = 16640,
              PB_G1 = 16768, PB_BE1 = 16896, PB_W2 = 17024, PB_A2S = 33408,
              PB_A2D = 33536, PB_B2 = 33664, PB_G2 = 33792, PB_BE2 = 33920,
              PB_L1W = 34048, PB_L1B = 50432, PB_L2W = 50560, PB_L2B = 50816,
              PB_TOTAL = 50818;

struct PtrPack { const void* p[16]; };

__device__ __forceinline__ float b2f(unsigned short u) {
  unsigned v = ((unsigned)u) << 16;
  float f;
  __builtin_memcpy(&f, &v, 4);
  return f;
}
__device__ __forceinline__ float b2f_lo(unsigned u) {
  unsigned v = u << 16;
  float f;
  __builtin_memcpy(&f, &v, 4);
  return f;
}
__device__ __forceinline__ float b2f_hi(unsigned u) {
  unsigned v = u & 0xffff0000u;
  float f;
  __builtin_memcpy(&f, &v, 4);
  return f;
}
__device__ __forceinline__ unsigned short f2b(float f) {
  unsigned x;
  __builtin_memcpy(&x, &f, 4);
  unsigned r = x + 0x7FFFu + ((x >> 16) & 1u);
  return (unsigned short)(r >> 16);
}

// packed dual-FMA: acc.{x,y} += {bf16lo(u), bf16hi(u)} * wp.{x,y}
__device__ __forceinline__ void pkfma(f32x2& acc, unsigned u, f32x2 wp) {
  f32x2 p = {b2f_lo(u), b2f_hi(u)};
  asm("v_pk_fma_f32 %0, %1, %2, %0" : "+v"(acc) : "v"(p), "v"(wp));
}

// prep (block-split fusion): blocks 0..NB-1 = edge phase (histogram, phase-A
// bucketing, packed hist dump); blocks NB..NB+255 = misc phase (dtype detect,
// params, Wt1, starts, zeros). Independent phases share one launch (gap saved).
__global__ __launch_bounds__(512) void k_prep(PtrPack pk, const unsigned short* __restrict__ xb,
                                              const int* __restrict__ batch,
                                              const int* __restrict__ esrc,
                                              const int* __restrict__ edst,
                                              int* __restrict__ flag,
                                              float* __restrict__ pb,
                                              int* __restrict__ starts,
                                              int* __restrict__ ctrs,
                                              unsigned char* __restrict__ hist,
                                              unsigned* __restrict__ buck, int* __restrict__ bcnt,
                                              unsigned short* __restrict__ Wt1,
                                              float* __restrict__ poolsum) {
  __shared__ unsigned hcnt[25000];   // 2 x u16 packed per word (edge blocks)
  __shared__ int bc[NR];
  __shared__ int cs;
  int bid = blockIdx.x, t = threadIdx.x;
  if (bid < NB) {
    int c = bid;
    if (t < NR) bc[t] = 0;
    for (int j = t; j < 25000; j += 512) hcnt[j] = 0u;
    __syncthreads();
    int e0 = c * EPB;
    for (int i = t; i < EPB; i += 512) {
      int e = e0 + i;
      int d = edst[e];
      if ((unsigned)d >= (unsigned)NN) continue;
      int s = esrc[e];
      if ((unsigned)s >= (unsigned)NN) s = 0;
      int sh = (d & 1) * 16;
      unsigned old = atomicAdd(&hcnt[d >> 1], 1u << sh);
      unsigned rank = (old >> sh) & 0xFFFFu;
      if (rank > 7u) continue;
      int r = d / RNG;
      int dl = d - r * RNG;
      int pos = atomicAdd(&bc[r], 1);
      if (pos < BCAP)
        buck[(c * NR + r) * BCAP + pos] = ((unsigned)s << 16) | ((unsigned)dl << 3) | rank;
    }
    __syncthreads();
    if (t < NR) bcnt[c * NR + t] = min(bc[t], BCAP);
    // packed hist dump: 4 counts per uint store (NN % 4 == 0)
    unsigned* hw = (unsigned*)(hist + c * NN);
    for (int j = t; j < NN / 4; j += 512) {
      unsigned w0 = hcnt[2 * j], w1 = hcnt[2 * j + 1];
      unsigned b0 = min(w0 & 0xFFFFu, 255u), b1 = min(w0 >> 16, 255u);
      unsigned b2 = min(w1 & 0xFFFFu, 255u), b3 = min(w1 >> 16, 255u);
      hw[j] = b0 | (b1 << 8) | (b2 << 16) | (b3 << 24);
    }
  } else {
    const int segoff[17] = {0, 16384, 16512, 16640, 16768, 16896, 17024, 33408,
                            33536, 33664, 33792, 33920, 34048, 50432, 50560, 50816, 50818};
    int c = bid - NB;
    if (t == 0) cs = 0;
    __syncthreads();
    int sane = 0;
    for (int i = t; i < 4096; i += 512) {
      float a = fabsf(b2f(xb[i]));
      if (a > 1e-4f && a < 100.f) sane++;
    }
    atomicAdd(&cs, sane);
    __syncthreads();
    int bf = (cs > 3482) ? 1 : 0;
    if (c == 0 && t == 0) *flag = bf;
    // params
    for (int j = t; j < 199; j += 512) {
      int i = c * 199 + j;
      if (i < PB_TOTAL) {
        int seg = 0;
        while (i >= segoff[seg + 1]) seg++;
        int k = i - segoff[seg];
        pb[i] = bf ? b2f(((const unsigned short*)pk.p[seg])[k]) : ((const float*)pk.p[seg])[k];
      }
    }
    // Wt1[n][k] = bf16(W1[k][n]): 64 elements per block
    for (int j = t; j < 64; j += 512) {
      int i = c * 64 + j;
      int n = i & 127, k = i >> 7;
      Wt1[n * 128 + k] = bf ? ((const unsigned short*)pk.p[0])[k * 128 + n]
                            : f2b(((const float*)pk.p[0])[k * 128 + n]);
    }
    // poolsum zero: 128 per block
    for (int j = t; j < 128; j += 512) poolsum[c * 128 + j] = 0.f;
    // starts
    for (int j = t; j < 196; j += 512) {
      int n = c * 196 + j;
      if (n < NN) {
        int bb = batch[n];
        bb = min(max(bb, 0), GG - 1);
        int bp = (n == 0) ? -1 : batch[n - 1];
        bp = min(max(bp, -1), GG - 1);
        for (int gg = bp + 1; gg <= bb; gg++) starts[gg] = n;
        if (n == NN - 1)
          for (int gg = bb + 1; gg <= GG; gg++) starts[gg] = NN;
      }
    }
    if (c == 255 && t < 8) ctrs[t] = 0;
  }
}

// MFMA GEMM: Y = X @ Wt^T + shiftW, B-fragments straight from global bf16 Wt[n][k].
__device__ __forceinline__ void gemm_body(float* cst, int bid,
                                          const unsigned short* __restrict__ Xb,
                                          const float* __restrict__ Xf, int bfm,
                                          const unsigned short* __restrict__ Wt,
                                          const float* __restrict__ shiftW,
                                          const float* __restrict__ aS,
                                          const float* __restrict__ aD,
                                          unsigned short* __restrict__ Y,
                                          float* __restrict__ as_, float* __restrict__ ad_) {
  int t = threadIdx.x;
  int row0 = bid * 64;
  int w = t >> 6, lane = t & 63;
  int m = lane & 15, quad = lane >> 4;
  int rA = min(row0 + w * 16 + m, NN - 1);
  short8 a4[4];
  if (bfm) {
    const short8* xp = (const short8*)(Xb + rA * 128);
#pragma unroll
    for (int kk = 0; kk < 4; kk++) a4[kk] = xp[kk * 4 + quad];
  } else {
#pragma unroll
    for (int kk = 0; kk < 4; kk++) {
      const float* xf = Xf + rA * 128 + kk * 32 + quad * 8;
#pragma unroll
      for (int j = 0; j < 8; j++) a4[kk][j] = (short)f2b(xf[j]);
    }
  }
  f32x4 acc[8] = {};
#pragma unroll
  for (int kk = 0; kk < 4; kk++) {
    int ko = kk * 32 + quad * 8;
#pragma unroll
    for (int n0 = 0; n0 < 8; n0++) {
      short8 b = *(const short8*)(Wt + (n0 * 16 + m) * 128 + ko);
      acc[n0] = __builtin_amdgcn_mfma_f32_16x16x32_bf16(a4[kk], b, acc[n0], 0, 0, 0);
    }
  }
  // C layout: col = lane&15, row = quad*4 + reg
#pragma unroll
  for (int n0 = 0; n0 < 8; n0++)
#pragma unroll
    for (int r = 0; r < 4; r++)
      cst[(w * 16 + quad * 4 + r) * 130 + n0 * 16 + m] = acc[n0][r];
  __syncthreads();
  int cg = t & 31, rg = t >> 5;
  int c0 = cg * 4;
  float a_s[4], a_d[4], sw[4];
#pragma unroll
  for (int j = 0; j < 4; j++) {
    a_s[j] = aS[c0 + j];
    a_d[j] = aD[c0 + j];
    sw[j] = shiftW[c0 + j];
  }
#pragma unroll
  for (int i = 0; i < 8; i++) {
    int rl = rg + i * 8;
    int row = row0 + rl;
    float v0 = cst[rl * 130 + c0 + 0] + sw[0];
    float v1 = cst[rl * 130 + c0 + 1] + sw[1];
    float v2 = cst[rl * 130 + c0 + 2] + sw[2];
    float v3 = cst[rl * 130 + c0 + 3] + sw[3];
    if (row < NN) {
      uint2 pk2;
      pk2.x = (unsigned)f2b(v0) | ((unsigned)f2b(v1) << 16);
      pk2.y = (unsigned)f2b(v2) | ((unsigned)f2b(v3) << 16);
      *reinterpret_cast<uint2*>(&Y[row * 128 + c0]) = pk2;
    }
    float ps = v0 * a_s[0] + v1 * a_s[1] + v2 * a_s[2] + v3 * a_s[3];
    float pd = v0 * a_d[0] + v1 * a_d[1] + v2 * a_d[2] + v3 * a_d[3];
    ps += __shfl_xor(ps, 1); ps += __shfl_xor(ps, 2); ps += __shfl_xor(ps, 4);
    pd += __shfl_xor(pd, 1); pd += __shfl_xor(pd, 2); pd += __shfl_xor(pd, 4);
    if ((cg & 7) == 0 && row < NN) {
      int hh = cg >> 3;
      as_[row * 4 + hh] = ps;
      ad_[row * 4 + hh] = pd;
    }
  }
}

// fused: blocks 0..195 = in-place base scan over hist (16-way batched loads);
// blocks 196.. = layer-1 GEMM.
__global__ __launch_bounds__(256) void k_basegemm(unsigned char* __restrict__ hist,
                                                  int* __restrict__ cnt,
                                                  const unsigned short* __restrict__ Xb,
                                                  const float* __restrict__ Xf,
                                                  const int* __restrict__ flagp,
                                                  const unsigned short* __restrict__ Wt,
                                                  const float* __restrict__ shiftW,
                                                  const float* __restrict__ aS,
                                                  const float* __restrict__ aD,
                                                  unsigned short* __restrict__ Y,
                                                  float* __restrict__ as_, float* __restrict__ ad_) {
  __shared__ float cst[64 * 130];
  int idx = blockIdx.x;
  if (idx < 196) {
    int d = idx * 256 + threadIdx.x;
    if (d >= NN) return;
    int run = 0;
    for (int b = 0; b < NB; b += 16) {
      unsigned char h[16];
#pragma unroll
      for (int j = 0; j < 16; j++) h[j] = hist[(b + j) * NN + d];   // 16 loads in flight
#pragma unroll
      for (int j = 0; j < 16; j++) {
        hist[(b + j) * NN + d] = (unsigned char)min(run, 255);      // in-place: becomes base
        run += h[j];
      }
    }
    cnt[d] = run;
  } else {
    gemm_body(cst, idx - 196, Xb, Xf, *flagp, Wt, shiftW, aS, aD, Y, as_, ad_);
  }
}

// phase-B fill alone: 256 XCD-affine blocks (range r = bid&7).
__global__ __launch_bounds__(256) void k_fill(const unsigned* __restrict__ buck,
                                              const int* __restrict__ bcnt,
                                              const unsigned char* __restrict__ base,
                                              unsigned short* __restrict__ adj) {
  int idx = blockIdx.x;
  int t = threadIdx.x;
  int r = idx & 7, g = idx >> 3;
  int dbase = r * RNG;
#pragma unroll 1
  for (int j = 0; j < 8; j++) {
    int c = g * 8 + j;
    int n = bcnt[c * NR + r];
    const unsigned* bk = buck + (c * NR + r) * BCAP;
    const unsigned char* bs = base + c * NN;
    for (int i = t; i < n; i += 256) {
      unsigned p = bk[i];
      int s = p >> 16;
      int dl = (p >> 3) & 0x1FFF;
      int rank = p & 7;
      int d = dbase + dl;
      int slot = (int)bs[d] + rank;
      if (slot < PAD) adj[d * PAD + slot] = (unsigned short)s;
    }
  }
}

__global__ __launch_bounds__(256) void k_gemm(const unsigned short* __restrict__ Xb,
                                              const unsigned short* __restrict__ Wt,
                                              const float* __restrict__ shiftW,
                                              const float* __restrict__ aS,
                                              const float* __restrict__ aD,
                                              unsigned short* __restrict__ Y,
                                              float* __restrict__ as_, float* __restrict__ ad_) {
  __shared__ float cst[64 * 130];
  gemm_body(cst, blockIdx.x, Xb, nullptr, 1, Wt, shiftW, aS, aD, Y, as_, ad_);
}

// one WAVE per dst (4 nodes / 256-thread block), wave-synchronous.
// BW-bound at ~3.5 TB/s fabric (r3-r6: MLP-forcing flat x3; 175 MB @ 3.5
// TB/s = 50µs ≈ 54 measured) — proven floor form.
__global__ __launch_bounds__(256) void k_agg(const unsigned short* __restrict__ adj,
                                             const int* __restrict__ cnt,
                                             const float4* __restrict__ asrc4,
                                             const float4* __restrict__ adst4,
                                             const uint4* __restrict__ hin4,
                                             const float* __restrict__ bias,
                                             unsigned short* __restrict__ out) {
  __shared__ float wq2[4][4][PAD];     // [wave][head][slot]
  __shared__ unsigned soffs[4][PAD];   // [wave][slot] = src*256 (byte offset)
  int t = threadIdx.x;
  int wid = t >> 6, lane = t & 63;
  int n = blockIdx.x * 4 + wid;     // grid = NN/4 exactly
  int deg = cnt[n];
  if (deg < 0) deg = 0;
  if (deg > PAD - 1) deg = PAD - 1;
  int tot = deg + 1;  // + self loop
  int W = (((tot + 3) >> 2) + 3) & ~3;  // per-group window, mult of 4, 4W <= PAD
  int WL = 4 * W;
  int beg = n * PAD;
  float4 ad4 = adst4[n];
  float ls0 = 0.f, ls1 = 0.f, ls2 = 0.f, ls3 = 0.f;
  for (int b = lane; b < WL; b += 64) {
    if (b < tot) {
      int s = (b < deg) ? (int)adj[beg + b] : n;
      if ((unsigned)s >= (unsigned)NN) s = n;
      float4 a = asrc4[s];
      float s0 = a.x + ad4.x; s0 = s0 > 0.f ? s0 : NEG * s0;
      float s1 = a.y + ad4.y; s1 = s1 > 0.f ? s1 : NEG * s1;
      float s2 = a.z + ad4.z; s2 = s2 > 0.f ? s2 : NEG * s2;
      float s3 = a.w + ad4.w; s3 = s3 > 0.f ? s3 : NEG * s3;
      float e0 = __expf(s0), e1 = __expf(s1), e2 = __expf(s2), e3 = __expf(s3);
      ls0 += e0; ls1 += e1; ls2 += e2; ls3 += e3;
      wq2[wid][0][b] = e0; wq2[wid][1][b] = e1;
      wq2[wid][2][b] = e2; wq2[wid][3][b] = e3;
      soffs[wid][b] = (unsigned)s * 256u;
    } else {
      wq2[wid][0][b] = 0.f; wq2[wid][1][b] = 0.f;
      wq2[wid][2][b] = 0.f; wq2[wid][3][b] = 0.f;
      soffs[wid][b] = (unsigned)n * 256u;
    }
  }
  // intra-wave LDS RAW ordering + compiler fence
  asm volatile("" ::: "memory");
  __builtin_amdgcn_wave_barrier();
  int g = lane >> 4, L = lane & 15, hd = L >> 2;
  const char* hb = (const char*)hin4;
  unsigned Loff = (unsigned)L * 16u;
  const float* wrow = &wq2[wid][hd][0];
  const unsigned* srow = &soffs[wid][0];
  f32x2 acc2[4] = {};
  int e0w = g * W, e1w = e0w + W;
  for (int e = e0w; e < e1w; e += 4) {
    f32x4 w4 = *(const f32x4*)(wrow + e);        // ds_read_b128
    uint4 o4 = *(const uint4*)(srow + e);        // ds_read_b128
    uint4 v1 = *(const uint4*)(hb + (o4.x + Loff));
    uint4 v2 = *(const uint4*)(hb + (o4.y + Loff));
    uint4 v3 = *(const uint4*)(hb + (o4.z + Loff));
    uint4 v4 = *(const uint4*)(hb + (o4.w + Loff));
    f32x2 p1 = {w4.x, w4.x}, p2 = {w4.y, w4.y}, p3 = {w4.z, w4.z}, p4 = {w4.w, w4.w};
    pkfma(acc2[0], v1.x, p1); pkfma(acc2[1], v1.y, p1);
    pkfma(acc2[2], v1.z, p1); pkfma(acc2[3], v1.w, p1);
    pkfma(acc2[0], v2.x, p2); pkfma(acc2[1], v2.y, p2);
    pkfma(acc2[2], v2.z, p2); pkfma(acc2[3], v2.w, p2);
    pkfma(acc2[0], v3.x, p3); pkfma(acc2[1], v3.y, p3);
    pkfma(acc2[2], v3.z, p3); pkfma(acc2[3], v3.w, p3);
    pkfma(acc2[0], v4.x, p4); pkfma(acc2[1], v4.y, p4);
    pkfma(acc2[2], v4.z, p4); pkfma(acc2[3], v4.w, p4);
  }
  // cross-group reduce: lanes L, L+16, L+32, L+48 hold the same 8 channels
#pragma unroll
  for (int j = 0; j < 4; j++) {
    acc2[j].x += __shfl_xor(acc2[j].x, 16);
    acc2[j].y += __shfl_xor(acc2[j].y, 16);
    acc2[j].x += __shfl_xor(acc2[j].x, 32);
    acc2[j].y += __shfl_xor(acc2[j].y, 32);
  }
  // softmax denominators: register-only butterfly
#pragma unroll
  for (int mm = 1; mm < 64; mm <<= 1) {
    ls0 += __shfl_xor(ls0, mm);
    ls1 += __shfl_xor(ls1, mm);
    ls2 += __shfl_xor(ls2, mm);
    ls3 += __shfl_xor(ls3, mm);
  }
  if (g == 0) {
    float den = (hd == 0) ? ls0 : (hd == 1) ? ls1 : (hd == 2) ? ls2 : ls3;
    float inv = 1.0f / (den + 1e-16f);
    const float4* bp = reinterpret_cast<const float4*>(bias + L * 8);
    float4 b0 = bp[0], b1 = bp[1];
    float o0 = acc2[0].x * inv + b0.x;
    float o1 = acc2[0].y * inv + b0.y;
    float o2 = acc2[1].x * inv + b0.z;
    float o3 = acc2[1].y * inv + b0.w;
    float o4 = acc2[2].x * inv + b1.x;
    float o5 = acc2[2].y * inv + b1.y;
    float o6 = acc2[3].x * inv + b1.z;
    float o7 = acc2[3].y * inv + b1.w;
    o0 = o0 > 0.f ? o0 : 0.f;
    o1 = o1 > 0.f ? o1 : 0.f;
    o2 = o2 > 0.f ? o2 : 0.f;
    o3 = o3 > 0.f ? o3 : 0.f;
    o4 = o4 > 0.f ? o4 : 0.f;
    o5 = o5 > 0.f ? o5 : 0.f;
    o6 = o6 > 0.f ? o6 : 0.f;
    o7 = o7 > 0.f ? o7 : 0.f;
    uint4 pk4;
    pk4.x = (unsigned)f2b(o0) | ((unsigned)f2b(o1) << 16);
    pk4.y = (unsigned)f2b(o2) | ((unsigned)f2b(o3) << 16);
    pk4.z = (unsigned)f2b(o4) | ((unsigned)f2b(o5) << 16);
    pk4.w = (unsigned)f2b(o6) | ((unsigned)f2b(o7) << 16);
    *reinterpret_cast<uint4*>(&out[n * 128 + L * 8]) = pk4;
  }
}

// BN partial sums, ZERO atomics, split-kernel handoff (r11 lesson: per-block
// __threadfence on non-coherent multi-XCD L2 costs ~67µs/dispatch — the
// KERNEL BOUNDARY is the cheap fence). Grid BNPB (stats only) or BNPB+GG
// (layer 2: + per-graph pooling blocks via starts[], no atomics).
__global__ __launch_bounds__(256) void k_bnpartial(const unsigned* __restrict__ x32,
                                                   float* __restrict__ partial,
                                                   const int* __restrict__ starts,
                                                   float* __restrict__ poolsum) {
  __shared__ float stg[4][256];
  int bid = blockIdx.x, t = threadIdx.x;
  int u = t & 63, ph = t >> 6;
  if (bid < BNPB) {
    int r0 = bid * BNPR, r1 = min(r0 + BNPR, NN);
    float s0 = 0.f, q0 = 0.f, s1 = 0.f, q1 = 0.f;
    for (int r = r0 + ph; r < r1; r += 4) {
      unsigned v = x32[r * 64 + u];
      float lo = b2f_lo(v), hi = b2f_hi(v);
      s0 += lo; q0 += lo * lo;
      s1 += hi; q1 += hi * hi;
    }
    stg[ph][2 * u] = s0;
    stg[ph][2 * u + 1] = s1;
    stg[ph][128 + 2 * u] = q0;
    stg[ph][128 + 2 * u + 1] = q1;
    __syncthreads();
    partial[bid * 256 + t] = stg[0][t] + stg[1][t] + stg[2][t] + stg[3][t];
  } else {
    int g = bid - BNPB;
    int b0 = starts[g], b1 = starts[g + 1];
    b0 = min(max(b0, 0), NN);
    b1 = min(max(b1, 0), NN);
    float p0 = 0.f, p1 = 0.f;
    for (int r = b0 + ph; r < b1; r += 4) {
      unsigned v = x32[r * 64 + u];
      p0 += b2f_lo(v);
      p1 += b2f_hi(v);
    }
    stg[ph][2 * u] = p0;
    stg[ph][2 * u + 1] = p1;
    __syncthreads();
    if (t < 128) poolsum[g * 128 + t] = stg[0][t] + stg[1][t] + stg[2][t] + stg[3][t];
  }
}

// BN finalize layer 1 (1 block): reduce partials, affine coefficients,
// Wt2/sw2 build (BN1 folded into layer-2 GEMM).
__global__ __launch_bounds__(256) void k_bnfinal(const float* __restrict__ partial,
                                                 const float* __restrict__ g, const float* __restrict__ b,
                                                 const float* __restrict__ W2f, float* __restrict__ sw2,
                                                 unsigned short* __restrict__ Wt2) {
  __shared__ float sums[256];
  __shared__ float shs[128];
  __shared__ float scs[128];
  int t = threadIdx.x;
  float acc = 0.f;
  for (int bb = 0; bb < BNPB; bb += 8) {
    float a0 = partial[(bb + 0) * 256 + t];
    float a1 = partial[(bb + 1) * 256 + t];
    float a2 = partial[(bb + 2) * 256 + t];
    float a3 = partial[(bb + 3) * 256 + t];
    float a4 = partial[(bb + 4) * 256 + t];
    float a5 = partial[(bb + 5) * 256 + t];
    float a6 = partial[(bb + 6) * 256 + t];
    float a7 = partial[(bb + 7) * 256 + t];
    acc += ((a0 + a1) + (a2 + a3)) + ((a4 + a5) + (a6 + a7));
  }
  sums[t] = acc;
  __syncthreads();
  if (t < 128) {
    float inv = 1.0f / NN;
    float mu = sums[t] * inv;
    float var = sums[128 + t] * inv - mu * mu;
    float rs = rsqrtf(var + BN_EPS);
    scs[t] = g[t] * rs;
    shs[t] = b[t] - mu * scs[t];
  }
  __syncthreads();
  if (t < 128) {
    float s = 0.f;
    for (int k = 0; k < 128; k++) s += shs[k] * W2f[k * 128 + t];
    sw2[t] = s;
  }
  // Wt2[n][k] = bf16(scale[k] * W2[k][n])
  for (int i = t; i < 16384; i += 256) {
    int n = i & 127, k = i >> 7;
    Wt2[n * 128 + k] = f2b(scs[k] * W2f[k * 128 + n]);
  }
}

// head with BN2-finalize fused in: each block redundantly reduces the
// L2-resident bnpart, derives scale2/shift2 in LDS, then computes its
// graph's pooled BN + MLP.
__global__ __launch_bounds__(256) void k_head(const float* __restrict__ partial,
                                              const float* __restrict__ poolsum,
                                              const int* __restrict__ starts,
                                              const float* __restrict__ g, const float* __restrict__ b,
                                              const float* __restrict__ L1W, const float* __restrict__ L1b,
                                              const float* __restrict__ L2W, const float* __restrict__ L2b,
                                              const int* __restrict__ flagp, void* __restrict__ outp) {
  __shared__ float sums[256];
  __shared__ float scs[128], shs[128];
  __shared__ float pooled[128];
  __shared__ float r0a[128], r1a[128];
  int gid = blockIdx.x, t = threadIdx.x;
  float acc = 0.f;
  for (int bb = 0; bb < BNPB; bb += 8) {
    float a0 = partial[(bb + 0) * 256 + t];
    float a1 = partial[(bb + 1) * 256 + t];
    float a2 = partial[(bb + 2) * 256 + t];
    float a3 = partial[(bb + 3) * 256 + t];
    float a4 = partial[(bb + 4) * 256 + t];
    float a5 = partial[(bb + 5) * 256 + t];
    float a6 = partial[(bb + 6) * 256 + t];
    float a7 = partial[(bb + 7) * 256 + t];
    acc += ((a0 + a1) + (a2 + a3)) + ((a4 + a5) + (a6 + a7));
  }
  sums[t] = acc;
  __syncthreads();
  if (t < 128) {
    float inv = 1.0f / NN;
    float mu = sums[t] * inv;
    float var = sums[128 + t] * inv - mu * mu;
    float rs = rsqrtf(var + BN_EPS);
    scs[t] = g[t] * rs;
    shs[t] = b[t] - mu * scs[t];
  }
  __syncthreads();
  int b0 = starts[gid], b1 = starts[gid + 1];
  b0 = min(max(b0, 0), NN);
  b1 = min(max(b1, 0), NN);
  int cnt = b1 - b0;
  if (t < 128) {
    float s = poolsum[gid * 128 + t];
    pooled[t] = (cnt > 0) ? (s / cnt) * scs[t] + shs[t] : 0.f;
  }
  __syncthreads();
  if (t < 128) {
    float z = L1b[t];
    for (int k = 0; k < 128; k++) z += pooled[k] * L1W[k * 128 + t];
    z = z > 0.f ? z : 0.f;
    r0a[t] = z * L2W[t * 2 + 0];
    r1a[t] = z * L2W[t * 2 + 1];
  }
  __syncthreads();
  for (int d = 64; d >= 1; d >>= 1) {
    if (t < d) {
      r0a[t] += r0a[t + d];
      r1a[t] += r1a[t + d];
    }
    __syncthreads();
  }
  if (t == 0) {
    float o0 = r0a[0] + L2b[0];
    float o1 = r1a[0] + L2b[1];
    if (*flagp) {
      unsigned short* ob = (unsigned short*)outp;
      ob[gid * 2 + 0] = f2b(o0);
      ob[gid * 2 + 1] = f2b(o1);
    } else {
      float* of = (float*)outp;
      of[gid * 2 + 0] = o0;
      of[gid * 2 + 1] = o1;
    }
  }
}

extern "C" void kernel_launch(void* const* d_in, const int* in_sizes, int n_in,
                              void* d_out, int out_size, void* d_ws, size_t ws_size,
                              hipStream_t stream) {
  (void)in_sizes; (void)n_in; (void)out_size; (void)ws_size;
  const int* ei = (const int*)d_in[1];
  const int* batch = (const int*)d_in[2];

  float* ws = (float*)d_ws;
  size_t o = 0;
  int* flag = (int*)(ws + o);   o += 16;
  int* ctrs = (int*)(ws + o);   o += 16;
  float* pb = ws + o;           o += 51200;
  float* bnpart = ws + o;       o += BNPB * 256;  // 512 KB partials, no atomics
  float* wzero = ws + o;        o += 128;
  float* sw2 = ws + o;          o += 128;
  unsigned short* Wt1 = (unsigned short*)(ws + o); o += 8192;
  unsigned short* Wt2 = (unsigned short*)(ws + o); o += 8192;
  float* poolsum = ws + o;      o += GG * 128;
  int* cnt = (int*)(ws + o);    o += 50016;
  int* starts = (int*)(ws + o); o += 512;
  int* bcnt = (int*)(ws + o);   o += 2048;
  float* asrc = ws + o;         o += 200000;
  float* adst = ws + o;         o += 200000;
  unsigned* buck = (unsigned*)(ws + o);            o += NB * NR * BCAP;  // 7.5 MB
  unsigned short* adj = (unsigned short*)(ws + o); o += NN * PAD / 2;    // 8 MB
  unsigned short* hA = (unsigned short*)(ws + o);  o += 3200000;         // 12.8 MB
  unsigned short* hB = (unsigned short*)(ws + o);  o += 3200000;         // 12.8 MB

  // hist/base share ONE buffer in hA-space (in-place scan): hA's real
  // lifetime starts at k_agg#1 output, after k_fill consumed base.
  unsigned char* hist = (unsigned char*)hA;

  const int* esrc = ei;
  const int* edst = ei + EE;

  PtrPack pk;
  for (int i = 0; i < 16; i++) pk.p[i] = d_in[3 + i];

  // fused prep: edge blocks (0..255) + misc blocks (256..511)
  k_prep<<<NB + 256, 512, 0, stream>>>(pk, (const unsigned short*)d_in[0], batch, esrc, edst,
                                       flag, pb, starts, ctrs, hist, buck, bcnt, Wt1, poolsum);

  // base scan (196 blocks, 16-way batched) || layer-1 MFMA gemm (782 blocks)
  k_basegemm<<<196 + 782, 256, 0, stream>>>(hist, cnt,
                                            (const unsigned short*)d_in[0], (const float*)d_in[0],
                                            flag, Wt1, wzero,
                                            pb + PB_A1S, pb + PB_A1D, hB, asrc, adst);
  k_fill<<<NB, 256, 0, stream>>>(buck, bcnt, hist, adj);
  k_agg<<<NN / 4, 256, 0, stream>>>(adj, cnt, (const float4*)asrc, (const float4*)adst,
                                    (const uint4*)hB, pb + PB_B1, hA);
  k_bnpartial<<<BNPB, 256, 0, stream>>>((const unsigned*)hA, bnpart, starts, nullptr);
  k_bnfinal<<<1, 256, 0, stream>>>(bnpart, pb + PB_G1, pb + PB_BE1,
                                   pb + PB_W2, sw2, Wt2);

  // layer 2 (BN1 folded into Wt2/sw2)
  k_gemm<<<782, 256, 0, stream>>>(hA, Wt2, sw2, pb + PB_A2S, pb + PB_A2D, hB, asrc, adst);
  k_agg<<<NN / 4, 256, 0, stream>>>(adj, cnt, (const float4*)asrc, (const float4*)adst,
                                    (const uint4*)hB, pb + PB_B2, hA);
  // stats partials + per-graph pooling (no atomics)
  k_bnpartial<<<BNPB + GG, 256, 0, stream>>>((const unsigned*)hA, bnpart, starts, poolsum);

  // head with fused BN2 finalize
  k_head<<<GG, 256, 0, stream>>>(bnpart, poolsum, starts,
                                 pb + PB_G2, pb + PB_BE2,
                                 pb + PB_L1W, pb + PB_L1B,
                                 pb + PB_L2W, pb + PB_L2B, flag, d_out);
}